// Round 1
// baseline (460.887 us; speedup 1.0000x reference)
//
#include <hip/hip_runtime.h>
#include <hip/hip_bf16.h>
#include <stdint.h>

#define B_   128
#define N_   196
#define E_   2048
#define D_   512
#define A_   512
#define MTOT (B_ * N_)   // 25088 = 392*64 exactly

typedef short  short8  __attribute__((ext_vector_type(8)));
typedef float  floatx4 __attribute__((ext_vector_type(4)));

__device__ __forceinline__ unsigned short f2bf(float f) {
    union { float f; uint32_t u; } v; v.f = f;
    uint32_t r = v.u + 0x7FFFu + ((v.u >> 16) & 1u);   // RNE
    return (unsigned short)(r >> 16);
}

// ---------------------------------------------------------------------------
// Kernel A2: We [2048][512] fp32 -> WeT [512][2048] bf16 (k-contiguous rows)
// ---------------------------------------------------------------------------
__global__ void transcvt_k(const float* __restrict__ We, unsigned short* __restrict__ WeT) {
    __shared__ float tile[32][33];
    const int e0 = blockIdx.x * 32, a0 = blockIdx.y * 32;
    const int t = threadIdx.x, tc = t & 31, tr = t >> 5;   // tr 0..7
#pragma unroll
    for (int i = 0; i < 4; ++i) {
        int r = tr + i * 8;
        tile[r][tc] = We[(size_t)(e0 + r) * A_ + a0 + tc];
    }
    __syncthreads();
#pragma unroll
    for (int i = 0; i < 4; ++i) {
        int r = tr + i * 8;
        WeT[(size_t)(a0 + r) * E_ + e0 + tc] = f2bf(tile[tc][r]);
    }
}

// ---------------------------------------------------------------------------
// Kernel A: att2p[b][a] = dh[b,:]@Wd[:,a] + bd[a] + be[a]   (fp32, tiny)
// ---------------------------------------------------------------------------
__launch_bounds__(512)
__global__ void att2_k(const float* __restrict__ dh, const float* __restrict__ Wd,
                       const float* __restrict__ bd, const float* __restrict__ be,
                       float* __restrict__ att2p) {
    const int b = blockIdx.x, t = threadIdx.x;
    __shared__ float sdh[D_];
    sdh[t] = dh[b * D_ + t];
    __syncthreads();
    float acc = 0.f;
#pragma unroll 8
    for (int d = 0; d < D_; ++d) acc += sdh[d] * Wd[(size_t)d * A_ + t];
    att2p[(size_t)b * A_ + t] = acc + bd[t] + be[t];
}

// ---------------------------------------------------------------------------
// Kernel B: fused bf16 MFMA GEMM (enc @ We) + tanh + dot(Wf) score epilogue.
// Block: 256 thr (4 waves), tile 64 rows x 256 cols, BK=32, K=2048.
// Wave w owns cols [cw0 + w*64, +64). Writes partial scores per col-half.
// ---------------------------------------------------------------------------
__launch_bounds__(256, 3)
__global__ void score_gemm(const float* __restrict__ enc,
                           const unsigned short* __restrict__ WeT,
                           const float* __restrict__ att2p,
                           const float* __restrict__ Wf,
                           float* __restrict__ scoresP) {
    __shared__ __align__(16) unsigned short sA[64 * 40];   // 32 k + 8 pad per row
    __shared__ __align__(16) unsigned short sB[256 * 32];  // 1024 slots of 16B, swizzled
    __shared__ float sPart[4][64];

    const int t   = threadIdx.x;
    const int w   = t >> 6;
    const int l   = t & 63;
    const int l15 = l & 15;
    const int q4  = l >> 4;
    const int row0 = blockIdx.y * 64;     // grid.y = 392
    const int cw0  = blockIdx.x * 256;    // grid.x = 2 (col halves adjacent in dispatch)

    floatx4 acc[4][4] = {};

    // A staging: 2 float4 loads per thread per K-step
    const int idx1 = t + 256;
    const int ar0 = t >> 3,    ac0 = (t & 7) * 4;
    const int ar1 = idx1 >> 3, ac1 = (idx1 & 7) * 4;
    const float* encA0 = enc + (size_t)(row0 + ar0) * E_ + ac0;
    const float* encA1 = enc + (size_t)(row0 + ar1) * E_ + ac1;

    // B staging: 4 global_load_lds (16B/lane) per wave per K-step.
    // slot s holds quarter q = (s&3)^((nloc>>2)&3) of row nloc = s>>2.
    const unsigned short* bsrc[4];
    int bdst[4];
#pragma unroll
    for (int j = 0; j < 4; ++j) {
        int s    = (w * 4 + j) * 64 + l;
        int nloc = s >> 2;
        int q    = (s & 3) ^ ((nloc >> 2) & 3);
        bsrc[j]  = WeT + (size_t)(cw0 + nloc) * E_ + q * 8;
        bdst[j]  = (w * 4 + j) * 1024;   // wave-uniform LDS byte base
    }

    for (int k0 = 0; k0 < E_; k0 += 32) {
#pragma unroll
        for (int j = 0; j < 4; ++j) {
            __builtin_amdgcn_global_load_lds(
                (const __attribute__((address_space(1))) uint32_t*)(bsrc[j] + k0),
                (__attribute__((address_space(3))) uint32_t*)((char*)sB + bdst[j]),
                16, 0, 0);
        }
        float4 v0 = *(const float4*)(encA0 + k0);
        float4 v1 = *(const float4*)(encA1 + k0);
        ushort4 h0 = { f2bf(v0.x), f2bf(v0.y), f2bf(v0.z), f2bf(v0.w) };
        ushort4 h1 = { f2bf(v1.x), f2bf(v1.y), f2bf(v1.z), f2bf(v1.w) };
        *(ushort4*)&sA[ar0 * 40 + ac0] = h0;
        *(ushort4*)&sA[ar1 * 40 + ac1] = h1;
        __syncthreads();

        short8 af[4], bfr[4];
#pragma unroll
        for (int mi = 0; mi < 4; ++mi)
            af[mi] = *(const short8*)&sA[(mi * 16 + l15) * 40 + q4 * 8];
#pragma unroll
        for (int ni = 0; ni < 4; ++ni) {
            int nloc = w * 64 + ni * 16 + l15;
            int slot = nloc * 4 + (q4 ^ ((nloc >> 2) & 3));
            bfr[ni] = *(const short8*)&sB[slot * 8];
        }
#pragma unroll
        for (int mi = 0; mi < 4; ++mi)
#pragma unroll
            for (int ni = 0; ni < 4; ++ni)
                acc[mi][ni] = __builtin_amdgcn_mfma_f32_16x16x32_bf16(
                    af[mi], bfr[ni], acc[mi][ni], 0, 0, 0);
        __syncthreads();
    }

    // Epilogue: s[m] += sum_n tanh(acc + att2p[b(m),n]) * Wf[n]  (partial over 256 cols)
    const int cbase = cw0 + w * 64;
    float wfv[4];
#pragma unroll
    for (int ni = 0; ni < 4; ++ni) wfv[ni] = Wf[cbase + ni * 16 + l15];

#pragma unroll
    for (int mi = 0; mi < 4; ++mi) {
#pragma unroll
        for (int r = 0; r < 4; ++r) {
            const int m    = mi * 16 + q4 * 4 + r;     // D layout: row=(l>>4)*4+reg
            const int grow = row0 + m;
            const int bb   = grow / N_;
            const float* a2 = att2p + (size_t)bb * A_ + cbase;
            float s = 0.f;
#pragma unroll
            for (int ni = 0; ni < 4; ++ni) {
                float v  = acc[mi][ni][r] + a2[ni * 16 + l15];
                float e  = __expf(2.f * v);
                float th = 1.f - 2.f / (e + 1.f);      // tanh(v)
                s += th * wfv[ni];
            }
            s += __shfl_xor(s, 1);
            s += __shfl_xor(s, 2);
            s += __shfl_xor(s, 4);
            s += __shfl_xor(s, 8);
            if (l15 == 0) sPart[w][m] = s;
        }
    }
    __syncthreads();
    if (t < 64) {
        float v = sPart[0][t] + sPart[1][t] + sPart[2][t] + sPart[3][t];
        scoresP[(size_t)blockIdx.x * MTOT + row0 + t] = v;
    }
}

// ---------------------------------------------------------------------------
// Kernel C0: softmax over N=196 per batch (bf bias dropped — softmax-invariant)
// ---------------------------------------------------------------------------
__global__ void softmax_k(const float* __restrict__ sp, float* __restrict__ alpha) {
    const int b = blockIdx.x, t = threadIdx.x;
    const int w = t >> 6, l = t & 63;
    __shared__ float red[8];
    float v = -3.0e38f;
    if (t < N_) v = sp[b * N_ + t] + sp[MTOT + b * N_ + t];
    float m = v;
#pragma unroll
    for (int off = 32; off >= 1; off >>= 1) m = fmaxf(m, __shfl_xor(m, off));
    if (l == 0) red[w] = m;
    __syncthreads();
    m = fmaxf(fmaxf(red[0], red[1]), fmaxf(red[2], red[3]));
    float e = 0.f;
    if (t < N_) e = __expf(v - m);
    float s = e;
#pragma unroll
    for (int off = 32; off >= 1; off >>= 1) s += __shfl_xor(s, off);
    if (l == 0) red[4 + w] = s;
    __syncthreads();
    s = red[4] + red[5] + red[6] + red[7];
    if (t < N_) alpha[b * N_ + t] = e / s;
}

// ---------------------------------------------------------------------------
// Kernel C1: context[b, :] = sum_n alpha[b,n] * enc[b,n,:]   (fp32 stream)
// grid (8 col-chunks of 256, 128 batches), 256 thr: tn=n-phase, tc=col/4
// ---------------------------------------------------------------------------
__launch_bounds__(256)
__global__ void context_k(const float* __restrict__ enc, const float* __restrict__ alpha,
                          float* __restrict__ ctx) {
    const int chunk = blockIdx.x, b = blockIdx.y;
    const int t = threadIdx.x, tn = t >> 6, tc = t & 63;
    __shared__ float  sAl[N_];
    __shared__ float4 sRed[256];
    if (t < N_) sAl[t] = alpha[b * N_ + t];
    __syncthreads();
    const float* base = enc + (size_t)b * N_ * E_ + chunk * 256 + tc * 4;
    float4 a = make_float4(0.f, 0.f, 0.f, 0.f);
#pragma unroll 7
    for (int n = tn; n < N_; n += 4) {
        float  al = sAl[n];
        float4 v  = *(const float4*)(base + (size_t)n * E_);
        a.x += al * v.x; a.y += al * v.y; a.z += al * v.z; a.w += al * v.w;
    }
    sRed[t] = a;
    __syncthreads();
    if (t < 64) {
        float4 r0 = sRed[t], r1 = sRed[t + 64], r2 = sRed[t + 128], r3 = sRed[t + 192];
        float4 o = make_float4(r0.x + r1.x + r2.x + r3.x, r0.y + r1.y + r2.y + r3.y,
                               r0.z + r1.z + r2.z + r3.z, r0.w + r1.w + r2.w + r3.w);
        *(float4*)(ctx + (size_t)b * E_ + chunk * 256 + t * 4) = o;
    }
}

// ---------------------------------------------------------------------------
extern "C" void kernel_launch(void* const* d_in, const int* in_sizes, int n_in,
                              void* d_out, int out_size, void* d_ws, size_t ws_size,
                              hipStream_t stream) {
    const float* enc = (const float*)d_in[0];
    const float* dh  = (const float*)d_in[1];
    const float* We  = (const float*)d_in[2];
    const float* be  = (const float*)d_in[3];
    const float* Wd  = (const float*)d_in[4];
    const float* bd  = (const float*)d_in[5];
    const float* Wf  = (const float*)d_in[6];
    // d_in[7] = bf: additive constant on scores, cancels in softmax; alpha is
    // the only score consumer, so it is dropped.

    float* out   = (float*)d_out;
    float* ctx   = out;              // [128, 2048]
    float* alpha = out + B_ * E_;    // [128, 196]

    char* ws = (char*)d_ws;
    unsigned short* WeT  = (unsigned short*)ws;                       // 2 MB
    float* att2p         = (float*)(ws + (2u << 20));                 // 256 KB
    float* scoresP       = (float*)(ws + (2u << 20) + (256u << 10));  // 2 x 25088 fp32

    transcvt_k <<<dim3(E_ / 32, A_ / 32), 256, 0, stream>>>(We, WeT);
    att2_k     <<<dim3(B_),              512, 0, stream>>>(dh, Wd, bd, be, att2p);
    score_gemm <<<dim3(2, MTOT / 64),    256, 0, stream>>>(enc, WeT, att2p, Wf, scoresP);
    softmax_k  <<<dim3(B_),              256, 0, stream>>>(scoresP, alpha);
    context_k  <<<dim3(E_ / 256, B_),    256, 0, stream>>>(enc, alpha, ctx);
}